// Round 8
// baseline (258.709 us; speedup 1.0000x reference)
//
#include <hip/hip_runtime.h>
#include <float.h>

// Problem constants (B=16, T=2048, D=256, K=1024)
constexpr int kD = 256;
constexpr int kK = 1024;
constexpr int kN = 16 * 2048;   // 32768 rows

using bf16x8 = __attribute__((ext_vector_type(8))) short;
using f32x16 = __attribute__((ext_vector_type(16))) float;
using u16x8  = __attribute__((ext_vector_type(8))) unsigned short;

__device__ __forceinline__ unsigned short f2bf(float x) {
    union { float f; unsigned u; } a; a.f = x;
    const unsigned u = a.u;
    return (unsigned short)((u + 0x7fffu + ((u >> 16) & 1u)) >> 16);   // RNE
}
__device__ __forceinline__ float bf2f(unsigned short b) {
    union { unsigned u; float f; } a; a.u = ((unsigned)b) << 16;
    return a.f;
}

// ---------------------------------------------------------------------------
// Fused split: blocks [0,512) split X, blocks [512,528) split E (+csqr).
// Image layout (validated R3-R7): for 64-row block RB, unit u in [0,2048):
//   l=u&63, f=(u>>6)&1, t16=u>>7
//   row = RB*64 + f*32 + (l&31); d0 = t16*16 + (l>>5)*8
//   shorts offset = RB*16384 + t16*1024 + f*512 + l*8   (d-chunk stride 1024)
// Key property: unit == one lane's 16B MFMA fragment slice -> frags can be
// loaded global->register directly (no LDS, no barriers in the GEMM).
__global__ void vq_split_all_kernel(const float* __restrict__ X, const float* __restrict__ E,
                                    unsigned short* __restrict__ xh, unsigned short* __restrict__ xm,
                                    unsigned short* __restrict__ xl,
                                    unsigned short* __restrict__ eh, unsigned short* __restrict__ em,
                                    unsigned short* __restrict__ el,
                                    float* __restrict__ csqr) {
    __shared__ float part[64][4];
    const int b   = blockIdx.x;
    const bool isE = b >= 512;
    const int RB  = isE ? b - 512 : b;
    const float* src = isE ? E : X;
    unsigned short* oh = isE ? eh : xh;
    unsigned short* om = isE ? em : xm;
    unsigned short* ol = isE ? el : xl;
    const int t = threadIdx.x;
    #pragma unroll
    for (int it = 0; it < 8; ++it) {
        const int u   = it * 256 + t;
        const int l   = u & 63;
        const int f   = (u >> 6) & 1;
        const int t16 = u >> 7;
        const int row = RB * 64 + f * 32 + (l & 31);
        const int d0  = t16 * 16 + (l >> 5) * 8;
        const float4 v0 = *reinterpret_cast<const float4*>(src + (size_t)row * kD + d0);
        const float4 v1 = *reinterpret_cast<const float4*>(src + (size_t)row * kD + d0 + 4);
        const float x[8] = {v0.x, v0.y, v0.z, v0.w, v1.x, v1.y, v1.z, v1.w};
        u16x8 H, M, L;
        #pragma unroll
        for (int e = 0; e < 8; ++e) {
            const unsigned short h = f2bf(x[e]);
            const float r1 = x[e] - bf2f(h);          // exact
            const unsigned short m = f2bf(r1);
            const float r2 = r1 - bf2f(m);            // exact
            const unsigned short lo = f2bf(r2);
            H[e] = (short)h; M[e] = (short)m; L[e] = (short)lo;
        }
        const size_t o = (size_t)RB * 16384 + (size_t)u * 8;
        *reinterpret_cast<u16x8*>(oh + o) = H;
        *reinterpret_cast<u16x8*>(om + o) = M;
        *reinterpret_cast<u16x8*>(ol + o) = L;
    }
    if (isE) {
        const int r = t >> 2, q = t & 3;
        const float* rp = E + (size_t)(RB * 64 + r) * kD + q * 64;
        float s = 0.0f;
        #pragma unroll
        for (int i = 0; i < 16; ++i) {
            const float4 v = reinterpret_cast<const float4*>(rp)[i];
            s += v.x * v.x + v.y * v.y + v.z * v.z + v.w * v.w;
        }
        part[r][q] = s;
        __syncthreads();
        if (t < 64) csqr[RB * 64 + t] = part[t][0] + part[t][1] + part[t][2] + part[t][3];
    }
}

// ---------------------------------------------------------------------------
// Pure-register MFMA distance GEMM: NO LDS, NO BARRIERS. Each wave owns a
// 128x64 output tile; fragments load global->VGPR directly (image is in
// fragment order). h-level prefetched one chunk ahead; m/lo levels JIT at
// cluster start (consumed passes 2-6, ~256-1000cyc slack vs ~200cyc L2 hit).
// Compiler emits per-use counted vmcnt -> AITER-style per-wave stream.
// dist(r,c) = csqr[c] - 2*dot  (||x||^2 dropped: argmin-invariant per row).
__global__ __launch_bounds__(256, 2) void vq_gemm_kernel(
    const unsigned short* __restrict__ xh, const unsigned short* __restrict__ xm,
    const unsigned short* __restrict__ xl,
    const unsigned short* __restrict__ eh, const unsigned short* __restrict__ em,
    const unsigned short* __restrict__ el,
    const float* __restrict__ csqr,
    unsigned long long* __restrict__ rowkey)
{
    const int tid  = threadIdx.x;
    const int lane = tid & 63;
    const int wid  = tid >> 6;            // 0..3
    const int wr   = wid >> 1;            // rows wr*128
    const int wc   = wid & 1;             // cols wc*64

    // XCD-bijective: 8 col-blocks of each 256-row panel land on one XCD.
    const int w    = blockIdx.x;          // 1024 blocks
    const int xcd  = w & 7;
    const int slot = w >> 3;              // 0..127
    const int rbp  = xcd * 16 + (slot >> 3);   // 0..127 row panel (256 rows)
    const int cb   = slot & 7;                 // 0..7  col block (128 codes)

    // Wave-local image base pointers (per-lane 16B slice baked in).
    const size_t laneoff = (size_t)lane * 8;
    const size_t abase = (size_t)(rbp * 4 + wr * 2) * 16384 + laneoff;
    const size_t bbase = (size_t)(cb * 2 + wc) * 16384 + laneoff;
    const unsigned short* pah = xh + abase;
    const unsigned short* pam = xm + abase;
    const unsigned short* pal = xl + abase;
    const unsigned short* pbh = eh + bbase;
    const unsigned short* pbm = em + bbase;
    const unsigned short* pbl = el + bbase;

    // Frag offsets (shorts): A(m,c) = (m>>1)*16384 + (m&1)*512 + c*1024
    //                        B(n,c) = n*512 + c*1024
#define FOA(m, c) ((size_t)((m) >> 1) * 16384 + ((m) & 1) * 512 + (size_t)(c) * 1024)
#define FOB(n, c) ((size_t)(n) * 512 + (size_t)(c) * 1024)
#define LD8(p) (*reinterpret_cast<const bf16x8*>(p))

    f32x16 acc[4][2];
    #pragma unroll
    for (int m = 0; m < 4; ++m) { acc[m][0] = (f32x16)0.0f; acc[m][1] = (f32x16)0.0f; }

#define MFMA_(a, b, c_) __builtin_amdgcn_mfma_f32_32x32x16_bf16(a, b, c_, 0, 0, 0)
    // 6-pass cluster, h-operands first (prefetched), then m (JIT, pass 2+),
    // lo last (JIT, pass 5+). Order change vs R5 is argmin-safe (no near-ties:
    // three prior distinct orders matched indices exactly).
    auto cluster = [&](const bf16x8* Ah, const bf16x8* Bh,
                       const bf16x8* Am, const bf16x8* Bm,
                       const bf16x8* Al, const bf16x8* Bl) {
        #pragma unroll
        for (int n = 0; n < 2; ++n)
            #pragma unroll
            for (int m = 0; m < 4; ++m) acc[m][n] = MFMA_(Ah[m], Bh[n], acc[m][n]); // hh
        #pragma unroll
        for (int n = 0; n < 2; ++n)
            #pragma unroll
            for (int m = 0; m < 4; ++m) acc[m][n] = MFMA_(Am[m], Bh[n], acc[m][n]); // mh
        #pragma unroll
        for (int n = 0; n < 2; ++n)
            #pragma unroll
            for (int m = 0; m < 4; ++m) acc[m][n] = MFMA_(Ah[m], Bm[n], acc[m][n]); // hm
        #pragma unroll
        for (int n = 0; n < 2; ++n)
            #pragma unroll
            for (int m = 0; m < 4; ++m) acc[m][n] = MFMA_(Am[m], Bm[n], acc[m][n]); // mm
        #pragma unroll
        for (int n = 0; n < 2; ++n)
            #pragma unroll
            for (int m = 0; m < 4; ++m) acc[m][n] = MFMA_(Ah[m], Bl[n], acc[m][n]); // hl
        #pragma unroll
        for (int n = 0; n < 2; ++n)
            #pragma unroll
            for (int m = 0; m < 4; ++m) acc[m][n] = MFMA_(Al[m], Bh[n], acc[m][n]); // lh
    };

    // h-level double buffer (register-renamed, no copies)
    bf16x8 hA[4], hB[2], gA[4], gB[2];
    #pragma unroll
    for (int m = 0; m < 4; ++m) hA[m] = LD8(pah + FOA(m, 0));
    #pragma unroll
    for (int n = 0; n < 2; ++n) hB[n] = LD8(pbh + FOB(n, 0));

    #pragma unroll 1
    for (int c = 0; c < 16; c += 2) {
        {   // chunk c: JIT m/lo; prefetch h(c+1) into g*
            bf16x8 mA[4], mB[2], lA[4], lB[2];
            #pragma unroll
            for (int m = 0; m < 4; ++m) { mA[m] = LD8(pam + FOA(m, c)); lA[m] = LD8(pal + FOA(m, c)); }
            #pragma unroll
            for (int n = 0; n < 2; ++n) { mB[n] = LD8(pbm + FOB(n, c)); lB[n] = LD8(pbl + FOB(n, c)); }
            #pragma unroll
            for (int m = 0; m < 4; ++m) gA[m] = LD8(pah + FOA(m, c + 1));
            #pragma unroll
            for (int n = 0; n < 2; ++n) gB[n] = LD8(pbh + FOB(n, c + 1));
            cluster(hA, hB, mA, mB, lA, lB);
        }
        {   // chunk c+1: JIT m/lo; prefetch h(c+2) into h*
            bf16x8 mA[4], mB[2], lA[4], lB[2];
            #pragma unroll
            for (int m = 0; m < 4; ++m) { mA[m] = LD8(pam + FOA(m, c + 1)); lA[m] = LD8(pal + FOA(m, c + 1)); }
            #pragma unroll
            for (int n = 0; n < 2; ++n) { mB[n] = LD8(pbm + FOB(n, c + 1)); lB[n] = LD8(pbl + FOB(n, c + 1)); }
            if (c + 2 < 16) {
                #pragma unroll
                for (int m = 0; m < 4; ++m) hA[m] = LD8(pah + FOA(m, c + 2));
                #pragma unroll
                for (int n = 0; n < 2; ++n) hB[n] = LD8(pbh + FOB(n, c + 2));
            }
            cluster(gA, gB, mA, mB, lA, lB);
        }
    }
#undef MFMA_
#undef LD8
#undef FOA
#undef FOB

    // Epilogue (validated R5-R7). C/D layout: col = lane&31,
    // row = (reg&3) + 8*(reg>>2) + 4*(lane>>5).
    const int lane31 = lane & 31;
    const int colbase = cb * 128 + wc * 64;
    const float cs0 = csqr[colbase + lane31];
    const float cs1 = csqr[colbase + 32 + lane31];
    const int rowbase = rbp * 256 + wr * 128 + 4 * (lane >> 5);

    #pragma unroll
    for (int m = 0; m < 4; ++m) {
        #pragma unroll
        for (int r = 0; r < 16; ++r) {
            float bv = fmaf(-2.0f, acc[m][0][r], cs0);
            int   bi = colbase + lane31;
            const float v1 = fmaf(-2.0f, acc[m][1][r], cs1);
            if (v1 < bv) { bv = v1; bi = colbase + 32 + lane31; }   // ascending col: '<' keeps first
            #pragma unroll
            for (int mk = 16; mk >= 1; mk >>= 1) {      // reduce within 32-lane half
                const float ov = __shfl_xor(bv, mk);
                const int   oi = __shfl_xor(bi, mk);
                if (ov < bv || (ov == bv && oi < bi)) { bv = ov; bi = oi; }
            }
            if (lane31 == 0) {
                const int row = rowbase + m * 32 + (r & 3) + 8 * (r >> 2);
                // monotone float->u32 key; (key<<32)|idx => min value, then min index
                unsigned kb = __float_as_uint(bv);
                kb = (bv < 0.0f) ? ~kb : (kb | 0x80000000u);
                atomicMin(&rowkey[row], ((unsigned long long)kb << 32) | (unsigned)bi);
            }
        }
    }
}

// ---------------------------------------------------------------------------
// Gather: read winning code from rowkey, emit z_q_x, z_q_x_bar, idxf.
__global__ void vq_gather_kernel(const float* __restrict__ E,
                                 const unsigned long long* __restrict__ rowkey,
                                 float* __restrict__ zq, float* __restrict__ zqb,
                                 float* __restrict__ idxf) {
    const int row = blockIdx.x * 4 + (threadIdx.x >> 6);
    const int lane = threadIdx.x & 63;
    const unsigned k = (unsigned)(rowkey[row] & 0xFFFFFFFFull);
    const float4 v = reinterpret_cast<const float4*>(E + (size_t)k * kD)[lane];
    reinterpret_cast<float4*>(zq + (size_t)row * kD)[lane] = v;
    reinterpret_cast<float4*>(zqb + (size_t)row * kD)[lane] = v;
    if (lane == 0) idxf[row] = (float)k;
}

// ---------------------------------------------------------------------------
extern "C" void kernel_launch(void* const* d_in, const int* in_sizes, int n_in,
                              void* d_out, int out_size, void* d_ws, size_t ws_size,
                              hipStream_t stream) {
    const float* X = (const float*)d_in[0];      // z_e_x  [N, D]
    const float* E = (const float*)d_in[1];      // embedding [K, D]

    float* out  = (float*)d_out;
    float* zq   = out;                           // [N*D]
    float* zqb  = out + (size_t)kN * kD;         // [N*D]
    float* idxf = out + 2 * (size_t)kN * kD;     // [N]

    // X images live in d_out [0,48MB); fully consumed by gemm before gather
    // overwrites (stream order).
    char* ob = (char*)d_out;
    unsigned short* XIh = (unsigned short*)ob;                   // 16 MB
    unsigned short* XIm = XIh + (size_t)kN * kD;                 // 16 MB
    unsigned short* XIl = XIm + (size_t)kN * kD;                 // 16 MB

    // ws: rowkey (256KB) | csqr (4KB) | E images (1.5MB)
    char* ws = (char*)d_ws;
    unsigned long long* rowkey = (unsigned long long*)ws;
    float* csqr = (float*)(ws + (size_t)kN * 8);
    unsigned short* EIh = (unsigned short*)(ws + (size_t)kN * 8 + 4096);
    unsigned short* EIm = EIh + (size_t)kK * kD;
    unsigned short* EIl = EIm + (size_t)kK * kD;

    hipMemsetAsync(rowkey, 0xFF, (size_t)kN * 8, stream);   // +inf keys
    vq_split_all_kernel<<<kN / 64 + kK / 64, 256, 0, stream>>>(
        X, E, XIh, XIm, XIl, EIh, EIm, EIl, csqr);
    vq_gemm_kernel<<<(kN / 256) * (kK / 128), 256, 0, stream>>>(
        XIh, XIm, XIl, EIh, EIm, EIl, csqr, rowkey);
    vq_gather_kernel<<<kN / 4, 256, 0, stream>>>(E, rowkey, zq, zqb, idxf);
}